// Round 1
// baseline (3779.646 us; speedup 1.0000x reference)
//
#include <hip/hip_runtime.h>
#include <cstdint>
#include <cstddef>

#define T_STEPS 1000
#define HID     128
#define DOUT    20
#define WPAD    129   // LDS row stride (128+1) to kill bank conflicts

// ---------------------------------------------------------------------------
// Pass 1: layer-1 dynamics. s1(t) = spike(x_t@Wi1^T + bi1 + s1(t-1)@Wh1^T + bh1)
// Writes spike bitmasks (2 x uint64 per sample-step) to global scratch.
// grid: 256 blocks x 256 threads. Block b owns samples {2b, 2b+1}.
// wave w (0..3): sample si = w>>1, output o = 64*(w&1) + lane.
// ---------------------------------------------------------------------------
extern "C" __global__ void __launch_bounds__(256, 1)
srnn_pass1(const float* __restrict__ x, const float* __restrict__ Wi1,
           const float* __restrict__ bi1, const float* __restrict__ Wh1,
           const float* __restrict__ bh1, unsigned long long* __restrict__ masks)
{
    extern __shared__ char smem[];
    float* WT1  = (float*)smem;                 // Wi1 transposed [128][WPAD]
    float* WTh1 = WT1 + HID * WPAD;             // Wh1 transposed [128][WPAD]
    float* xs   = WTh1 + HID * WPAD;            // x staging [2 buf][2 samp][128]
    unsigned long long* mb =
        (unsigned long long*)(xs + 2 * 2 * HID); // mask dbl-buf [2][2 samp][2 half]

    const int tid  = threadIdx.x;
    const int w    = tid >> 6, lane = tid & 63;
    const int si   = w >> 1,   half = w & 1;
    const int o    = (half << 6) + lane;
    const int s    = 2 * blockIdx.x + si;
    const int xe   = tid & 127;                  // element this thread stages

    // Stage transposed weights (coalesced global read, conflict-free LDS write).
    for (int idx = tid; idx < HID * HID; idx += 256) {
        int r = idx >> 7, k = idx & 127;         // W[r][k]
        WT1 [k * WPAD + r] = Wi1[idx];
        WTh1[k * WPAD + r] = Wh1[idx];
    }
    if (tid < 8) mb[tid] = 0ULL;                 // s1(−1) = 0
    const float my_bi1 = bi1[o], my_bh1 = bh1[o];

    const float* xrow = x + (size_t)s * (T_STEPS * HID);
    float xreg = xrow[xe];                       // prefetch t=0
    __syncthreads();

    for (int t = 0; t < T_STEPS; ++t) {
        const int buf = t & 1;
        xs[(buf * 2 + si) * HID + xe] = xreg;
        __syncthreads();                          // x(t) + mask(t-1) visible
        if (t + 1 < T_STEPS) xreg = xrow[(size_t)(t + 1) * HID + xe];

        // dense: dot(x_t, Wi1[o,:]) with 4 partial accumulators
        const float* xv = xs + (buf * 2 + si) * HID;
        float a0 = 0.f, a1 = 0.f, a2 = 0.f, a3 = 0.f;
        #pragma unroll 8
        for (int k = 0; k < HID; k += 4) {
            float4 xk = *(const float4*)(xv + k);
            a0 = fmaf(xk.x, WT1[(k + 0) * WPAD + o], a0);
            a1 = fmaf(xk.y, WT1[(k + 1) * WPAD + o], a1);
            a2 = fmaf(xk.z, WT1[(k + 2) * WPAD + o], a2);
            a3 = fmaf(xk.w, WT1[(k + 3) * WPAD + o], a3);
        }
        float dense = (a0 + a1) + (a2 + a3);

        // sparse recurrent: sum Wh1[o][j] over active j (ascending, == dense order)
        float rec = 0.f;
        unsigned long long m0 = mb[((buf ^ 1) * 2 + si) * 2 + 0];
        unsigned long long m1 = mb[((buf ^ 1) * 2 + si) * 2 + 1];
        while (m0) { int j = __builtin_ctzll(m0); m0 &= m0 - 1; rec += WTh1[j * WPAD + o]; }
        while (m1) { int j = __builtin_ctzll(m1); m1 &= m1 - 1; rec += WTh1[(64 + j) * WPAD + o]; }

        float h = ((dense + my_bi1) + rec) + my_bh1;   // reference add order
        unsigned long long bal = __ballot(h >= 1.0f);
        if (lane == 0) {
            mb[(buf * 2 + si) * 2 + half] = bal;
            masks[((size_t)s * T_STEPS + t) * 2 + half] = bal;
        }
        __syncthreads();                          // mask(t) ready for t+1
    }
}

// ---------------------------------------------------------------------------
// Pass 2: layer-2 dynamics + output accumulation. All matmuls are sparse
// (binary spike inputs). acc += s2@Wo^T; acc += bo each step; out = acc/T.
// ---------------------------------------------------------------------------
extern "C" __global__ void __launch_bounds__(256, 1)
srnn_pass2(const unsigned long long* __restrict__ masks,
           const float* __restrict__ Wi2, const float* __restrict__ bi2,
           const float* __restrict__ Wh2, const float* __restrict__ bh2,
           const float* __restrict__ Wo,  const float* __restrict__ bo,
           float* __restrict__ out)
{
    extern __shared__ char smem[];
    float* WTi2 = (float*)smem;                  // Wi2 transposed [128][WPAD]
    float* WTh2 = WTi2 + HID * WPAD;             // Wh2 transposed [128][WPAD]
    float* WoT  = WTh2 + HID * WPAD;             // Wo transposed  [128][21]
    unsigned long long* mb = (unsigned long long*)(WoT + HID * 21);

    const int tid  = threadIdx.x;
    const int w    = tid >> 6, lane = tid & 63;
    const int si   = w >> 1,   half = w & 1;
    const int o    = (half << 6) + lane;
    const int s    = 2 * blockIdx.x + si;

    for (int idx = tid; idx < HID * HID; idx += 256) {
        int r = idx >> 7, k = idx & 127;
        WTi2[k * WPAD + r] = Wi2[idx];
        WTh2[k * WPAD + r] = Wh2[idx];
    }
    for (int idx = tid; idx < DOUT * HID; idx += 256) {
        int r = idx >> 7, k = idx & 127;         // Wo[r][k], r < 20
        WoT[k * 21 + r] = Wo[idx];
    }
    if (tid < 8) mb[tid] = 0ULL;                 // s2(−1) = 0
    const float my_bi2 = bi2[o], my_bh2 = bh2[o];
    const bool  accthr = (half == 0) && (lane < DOUT);
    const float my_bo  = accthr ? bo[lane] : 0.f;
    float acc = 0.f;

    const ulonglong2* mrow = (const ulonglong2*)masks + (size_t)s * T_STEPS;
    ulonglong2 s1m = mrow[0];                    // prefetch t=0
    __syncthreads();

    for (int t = 0; t < T_STEPS; ++t) {
        const int buf = t & 1;
        const ulonglong2 cm = s1m;
        if (t + 1 < T_STEPS) s1m = mrow[t + 1];

        float A = 0.f, B = 0.f;
        unsigned long long m0 = cm.x, m1 = cm.y;
        while (m0) { int j = __builtin_ctzll(m0); m0 &= m0 - 1; A += WTi2[j * WPAD + o]; }
        while (m1) { int j = __builtin_ctzll(m1); m1 &= m1 - 1; A += WTi2[(64 + j) * WPAD + o]; }
        unsigned long long r0 = mb[((buf ^ 1) * 2 + si) * 2 + 0];
        unsigned long long r1 = mb[((buf ^ 1) * 2 + si) * 2 + 1];
        while (r0) { int j = __builtin_ctzll(r0); r0 &= r0 - 1; B += WTh2[j * WPAD + o]; }
        while (r1) { int j = __builtin_ctzll(r1); r1 &= r1 - 1; B += WTh2[(64 + j) * WPAD + o]; }

        float h = ((A + my_bi2) + B) + my_bh2;   // reference add order
        unsigned long long bal = __ballot(h >= 1.0f);
        if (lane == 0) mb[(buf * 2 + si) * 2 + half] = bal;
        __syncthreads();                          // s2(t) mask complete

        if (accthr) {
            unsigned long long q0 = mb[(buf * 2 + si) * 2 + 0];
            unsigned long long q1 = mb[(buf * 2 + si) * 2 + 1];
            float d = 0.f;
            while (q0) { int j = __builtin_ctzll(q0); q0 &= q0 - 1; d += WoT[j * 21 + lane]; }
            while (q1) { int j = __builtin_ctzll(q1); q1 &= q1 - 1; d += WoT[(64 + j) * 21 + lane]; }
            acc += d;                             // acc = (acc + dot) ...
            acc += my_bo;                         //        ... + bo
        }
        __syncthreads();
    }
    if (accthr) out[s * DOUT + lane] = acc / (float)T_STEPS;
}

// ---------------------------------------------------------------------------
extern "C" void kernel_launch(void* const* d_in, const int* in_sizes, int n_in,
                              void* d_out, int out_size, void* d_ws, size_t ws_size,
                              hipStream_t stream) {
    const float* x   = (const float*)d_in[0];
    const float* Wi1 = (const float*)d_in[1];
    const float* bi1 = (const float*)d_in[2];
    const float* Wh1 = (const float*)d_in[3];
    const float* bh1 = (const float*)d_in[4];
    const float* Wi2 = (const float*)d_in[5];
    const float* bi2 = (const float*)d_in[6];
    const float* Wh2 = (const float*)d_in[7];
    const float* bh2 = (const float*)d_in[8];
    const float* Wo  = (const float*)d_in[9];
    const float* bo  = (const float*)d_in[10];
    float* out = (float*)d_out;
    unsigned long long* masks = (unsigned long long*)d_ws;  // 512*1000*2 u64 = 8.2 MB

    const int lds1 = (2 * HID * WPAD + 2 * 2 * HID) * 4 + 8 * 8;
    const int lds2 = (2 * HID * WPAD + HID * 21) * 4 + 8 * 8;
    hipFuncSetAttribute((const void*)srnn_pass1,
                        hipFuncAttributeMaxDynamicSharedMemorySize, lds1);
    hipFuncSetAttribute((const void*)srnn_pass2,
                        hipFuncAttributeMaxDynamicSharedMemorySize, lds2);

    srnn_pass1<<<256, 256, lds1, stream>>>(x, Wi1, bi1, Wh1, bh1, masks);
    srnn_pass2<<<256, 256, lds2, stream>>>(masks, Wi2, bi2, Wh2, bh2, Wo, bo, out);
}

// Round 2
// 1765.963 us; speedup vs baseline: 2.1403x; 2.1403x over previous
//
#include <hip/hip_runtime.h>
#include <cstdint>
#include <cstddef>

#define T_STEPS 1000
#define NS      512
#define HID     128
#define DOUT    20
#define XPAD    129   // x tile row pad (bank-conflict-free lane reads)
#define WPAD    129   // transposed-weight row pad

// ---------------------------------------------------------------------------
// Pass 0: dense precompute D[row][o] = dot(x_row, Wi1[o][:]) using the exact
// 4-accumulator stride-4 fmaf chain that was verified bit-exact vs numpy in
// round 1 (a_i sums k ≡ i mod 4 ascending; final (a0+a1)+(a2+a3)). DO NOT
// change this order: spike thresholds make the dynamics chaotic to 1-ulp flips.
// Block: 512 threads (8 waves) x 128 rows. Wave w -> o in [16w, 16w+16),
// lane ln -> rows {ln, 64+ln}. grid = 4*Tc blocks (rows flat over chunk).
// ---------------------------------------------------------------------------
extern "C" __global__ void __launch_bounds__(512, 1)
srnn_dense(const float* __restrict__ x, const float* __restrict__ Wi1,
           float* __restrict__ D, int t0, int Tc)
{
    extern __shared__ float sm[];
    float* xs = sm;                    // [128 rows][XPAD]
    float* Wl = sm + 128 * XPAD;       // Wi1 row-major [128][128]
    const int tid = threadIdx.x;
    const int w = tid >> 6, ln = tid & 63;
    const int rb = blockIdx.x * 128;   // chunk-row base

    for (int i = tid; i < HID * HID / 4; i += 512)
        ((float4*)Wl)[i] = ((const float4*)Wi1)[i];
    for (int i = tid; i < 128 * 32; i += 512) {
        int r = i >> 5, kq = i & 31;
        int cr = rb + r;
        int s = cr / Tc, trel = cr - s * Tc;     // chunk row -> (sample, t)
        float4 v = ((const float4*)x)[((size_t)s * T_STEPS + t0 + trel) * 32 + kq];
        float* dst = &xs[r * XPAD + 4 * kq];
        dst[0] = v.x; dst[1] = v.y; dst[2] = v.z; dst[3] = v.w;
    }
    __syncthreads();

    const float* xr0 = xs + ln * XPAD;
    const float* xr1 = xs + (64 + ln) * XPAD;
    for (int og = 0; og < 4; ++og) {
        const int o = 16 * w + 4 * og;
        float a[2][4][4];
        #pragma unroll
        for (int r = 0; r < 2; ++r)
            #pragma unroll
            for (int j = 0; j < 4; ++j)
                #pragma unroll
                for (int i = 0; i < 4; ++i) a[r][j][i] = 0.f;

        #pragma unroll 4
        for (int k = 0; k < HID; k += 4) {
            float4 wv[4];
            #pragma unroll
            for (int j = 0; j < 4; ++j)
                wv[j] = *(const float4*)&Wl[(o + j) * HID + k];   // wave-uniform b128
            float xa0[4], xa1[4];
            #pragma unroll
            for (int i = 0; i < 4; ++i) { xa0[i] = xr0[k + i]; xa1[i] = xr1[k + i]; }
            #pragma unroll
            for (int j = 0; j < 4; ++j) {
                a[0][j][0] = fmaf(xa0[0], wv[j].x, a[0][j][0]);
                a[0][j][1] = fmaf(xa0[1], wv[j].y, a[0][j][1]);
                a[0][j][2] = fmaf(xa0[2], wv[j].z, a[0][j][2]);
                a[0][j][3] = fmaf(xa0[3], wv[j].w, a[0][j][3]);
                a[1][j][0] = fmaf(xa1[0], wv[j].x, a[1][j][0]);
                a[1][j][1] = fmaf(xa1[1], wv[j].y, a[1][j][1]);
                a[1][j][2] = fmaf(xa1[2], wv[j].z, a[1][j][2]);
                a[1][j][3] = fmaf(xa1[3], wv[j].w, a[1][j][3]);
            }
        }
        #pragma unroll
        for (int r = 0; r < 2; ++r) {
            float4 dv;
            dv.x = (a[r][0][0] + a[r][0][1]) + (a[r][0][2] + a[r][0][3]);
            dv.y = (a[r][1][0] + a[r][1][1]) + (a[r][1][2] + a[r][1][3]);
            dv.z = (a[r][2][0] + a[r][2][1]) + (a[r][2][2] + a[r][2][3]);
            dv.w = (a[r][3][0] + a[r][3][1]) + (a[r][3][2] + a[r][3][3]);
            *(float4*)&D[(size_t)(rb + 64 * r + ln) * HID + o] = dv;
        }
    }
}

// ---------------------------------------------------------------------------
// Pass 1: layer-1 recurrence. One wave per sample; lane ln owns neurons
// {ln, 64+ln}. Spike masks live in registers via ballots -> NO barriers and
// no LDS traffic in the t-loop except the sparse Wh1 sums (ascending j,
// bit-exact). D streamed with an 8-deep register prefetch pipeline.
// ---------------------------------------------------------------------------
extern "C" __global__ void __launch_bounds__(128, 1)
srnn_layer1(const float* __restrict__ D, const float* __restrict__ Wh1,
            const float* __restrict__ bi1, const float* __restrict__ bh1,
            ulonglong2* __restrict__ masks, ulonglong2* __restrict__ state,
            int t0, int Tc, int first)
{
    extern __shared__ float WT[];      // [j][o] transposed Wh1, rows padded WPAD
    const int tid = threadIdx.x, w = tid >> 6, ln = tid & 63;
    const int s = 2 * blockIdx.x + w;

    for (int i = tid; i < HID * HID / 4; i += 128) {
        int o = i >> 5, jq = i & 31;
        float4 v = ((const float4*)Wh1)[i];
        WT[(4 * jq + 0) * WPAD + o] = v.x; WT[(4 * jq + 1) * WPAD + o] = v.y;
        WT[(4 * jq + 2) * WPAD + o] = v.z; WT[(4 * jq + 3) * WPAD + o] = v.w;
    }
    const float bil = bi1[ln], bih = bi1[64 + ln];
    const float bhl = bh1[ln], bhh = bh1[64 + ln];
    unsigned long long m0 = 0ULL, m1 = 0ULL;
    if (!first) { ulonglong2 st = state[s]; m0 = st.x; m1 = st.y; }

    const float* Drow = D + (size_t)s * Tc * HID;
    float dl[8], dh[8];
    #pragma unroll
    for (int p = 0; p < 8; ++p) {
        int ti = p < Tc ? p : Tc - 1;
        dl[p] = Drow[ti * HID + ln];
        dh[p] = Drow[ti * HID + 64 + ln];
    }
    __syncthreads();

    for (int tt = 0; tt < Tc; tt += 8) {
        #pragma unroll
        for (int u = 0; u < 8; ++u) {
            int t = tt + u;
            if (t >= Tc) break;                       // wave-uniform
            float dense_l = dl[u], dense_h = dh[u];
            int tp = (t + 8 < Tc) ? t + 8 : Tc - 1;   // clamped prefetch
            dl[u] = Drow[tp * HID + ln];
            dh[u] = Drow[tp * HID + 64 + ln];

            float rl = 0.f, rh = 0.f;                 // ascending-j, bit-exact
            unsigned long long mm = m0;
            while (mm) { int j = __builtin_ctzll(mm); mm &= mm - 1;
                rl += WT[j * WPAD + ln]; rh += WT[j * WPAD + 64 + ln]; }
            mm = m1;
            while (mm) { int j = 64 + __builtin_ctzll(mm); mm &= mm - 1;
                rl += WT[j * WPAD + ln]; rh += WT[j * WPAD + 64 + ln]; }

            float hl = ((dense_l + bil) + rl) + bhl;  // reference add order
            float hh = ((dense_h + bih) + rh) + bhh;
            m0 = __ballot(hl >= 1.0f);
            m1 = __ballot(hh >= 1.0f);
            if (ln == 0) {
                ulonglong2 mv; mv.x = m0; mv.y = m1;
                masks[(size_t)s * T_STEPS + (t0 + t)] = mv;
            }
        }
    }
    if (ln == 0) { ulonglong2 st; st.x = m0; st.y = m1; state[s] = st; }
}

// ---------------------------------------------------------------------------
// Pass 2: layer-2 recurrence + output accumulation. Fully sparse; masks in
// registers (ballots), 8-deep s1-mask prefetch; no barriers in t-loop.
// ---------------------------------------------------------------------------
extern "C" __global__ void __launch_bounds__(128, 1)
srnn_layer2(const ulonglong2* __restrict__ masks,
            const float* __restrict__ Wi2, const float* __restrict__ bi2,
            const float* __restrict__ Wh2, const float* __restrict__ bh2,
            const float* __restrict__ Wo,  const float* __restrict__ bo,
            float* __restrict__ out)
{
    extern __shared__ float sm2[];
    float* WI  = sm2;                       // Wi2^T [j][o], pad WPAD
    float* WH  = sm2 + HID * WPAD;          // Wh2^T [j][o], pad WPAD
    float* WOt = sm2 + 2 * HID * WPAD;      // Wo^T  [j][20]
    const int tid = threadIdx.x, w = tid >> 6, ln = tid & 63;
    const int s = 2 * blockIdx.x + w;

    for (int i = tid; i < HID * HID / 4; i += 128) {
        int o = i >> 5, jq = i & 31;
        float4 a = ((const float4*)Wi2)[i];
        WI[(4 * jq + 0) * WPAD + o] = a.x; WI[(4 * jq + 1) * WPAD + o] = a.y;
        WI[(4 * jq + 2) * WPAD + o] = a.z; WI[(4 * jq + 3) * WPAD + o] = a.w;
        float4 b = ((const float4*)Wh2)[i];
        WH[(4 * jq + 0) * WPAD + o] = b.x; WH[(4 * jq + 1) * WPAD + o] = b.y;
        WH[(4 * jq + 2) * WPAD + o] = b.z; WH[(4 * jq + 3) * WPAD + o] = b.w;
    }
    for (int i = tid; i < DOUT * HID / 4; i += 128) {
        int o = i >> 5, jq = i & 31;
        float4 v = ((const float4*)Wo)[i];
        WOt[(4 * jq + 0) * DOUT + o] = v.x; WOt[(4 * jq + 1) * DOUT + o] = v.y;
        WOt[(4 * jq + 2) * DOUT + o] = v.z; WOt[(4 * jq + 3) * DOUT + o] = v.w;
    }
    const float bil = bi2[ln], bih = bi2[64 + ln];
    const float bhl = bh2[ln], bhh = bh2[64 + ln];
    const bool  oth = (ln < DOUT);
    const float bol = oth ? bo[ln] : 0.f;

    const ulonglong2* mrow = masks + (size_t)s * T_STEPS;
    ulonglong2 mb[8];
    #pragma unroll
    for (int p = 0; p < 8; ++p) mb[p] = mrow[p];
    unsigned long long p0 = 0ULL, p1 = 0ULL;
    float acc = 0.f;
    __syncthreads();

    for (int tt = 0; tt < T_STEPS; tt += 8) {
        #pragma unroll
        for (int u = 0; u < 8; ++u) {
            int t = tt + u;
            ulonglong2 s1 = mb[u];
            int tp = (t + 8 < T_STEPS) ? t + 8 : T_STEPS - 1;
            mb[u] = mrow[tp];

            float Al = 0.f, Ah = 0.f;                 // s1 @ Wi2^T (ascending)
            unsigned long long mm = s1.x;
            while (mm) { int j = __builtin_ctzll(mm); mm &= mm - 1;
                Al += WI[j * WPAD + ln]; Ah += WI[j * WPAD + 64 + ln]; }
            mm = s1.y;
            while (mm) { int j = 64 + __builtin_ctzll(mm); mm &= mm - 1;
                Al += WI[j * WPAD + ln]; Ah += WI[j * WPAD + 64 + ln]; }

            float Bl = 0.f, Bh = 0.f;                 // s2 @ Wh2^T (ascending)
            mm = p0;
            while (mm) { int j = __builtin_ctzll(mm); mm &= mm - 1;
                Bl += WH[j * WPAD + ln]; Bh += WH[j * WPAD + 64 + ln]; }
            mm = p1;
            while (mm) { int j = 64 + __builtin_ctzll(mm); mm &= mm - 1;
                Bl += WH[j * WPAD + ln]; Bh += WH[j * WPAD + 64 + ln]; }

            float hl = ((Al + bil) + Bl) + bhl;       // reference add order
            float hh = ((Ah + bih) + Bh) + bhh;
            p0 = __ballot(hl >= 1.0f);
            p1 = __ballot(hh >= 1.0f);

            if (oth) {                                 // s2 @ Wo^T + bo
                float d = 0.f;
                unsigned long long q = p0;
                while (q) { int j = __builtin_ctzll(q); q &= q - 1; d += WOt[j * DOUT + ln]; }
                q = p1;
                while (q) { int j = 64 + __builtin_ctzll(q); q &= q - 1; d += WOt[j * DOUT + ln]; }
                acc += d;                              // (acc + dot) ...
                acc += bol;                            //  ... + bo
            }
        }
    }
    if (oth) out[s * DOUT + ln] = acc / (float)T_STEPS;
}

// ---------------------------------------------------------------------------
extern "C" void kernel_launch(void* const* d_in, const int* in_sizes, int n_in,
                              void* d_out, int out_size, void* d_ws, size_t ws_size,
                              hipStream_t stream) {
    const float* x   = (const float*)d_in[0];
    const float* Wi1 = (const float*)d_in[1];
    const float* bi1 = (const float*)d_in[2];
    const float* Wh1 = (const float*)d_in[3];
    const float* bh1 = (const float*)d_in[4];
    const float* Wi2 = (const float*)d_in[5];
    const float* bi2 = (const float*)d_in[6];
    const float* Wh2 = (const float*)d_in[7];
    const float* bh2 = (const float*)d_in[8];
    const float* Wo  = (const float*)d_in[9];
    const float* bo  = (const float*)d_in[10];
    float* out = (float*)d_out;

    // ws layout: [masks 8.192 MB][layer1 state 8 KB][D chunk buffer]
    const size_t mask_bytes  = (size_t)NS * T_STEPS * sizeof(ulonglong2);
    const size_t state_bytes = (size_t)NS * sizeof(ulonglong2);
    ulonglong2* masks = (ulonglong2*)d_ws;
    ulonglong2* state = (ulonglong2*)((char*)d_ws + mask_bytes);
    float* D = (float*)((char*)d_ws + mask_bytes + state_bytes);

    size_t avail = ws_size > mask_bytes + state_bytes
                 ? ws_size - mask_bytes - state_bytes : 0;
    const size_t bytes_per_t = (size_t)NS * HID * sizeof(float);  // 256 KB
    long tcmax = (long)(avail / bytes_per_t);
    static const int divs[] = {1000, 500, 250, 200, 125, 100, 50, 40, 25, 20, 10, 8, 5, 4, 2, 1};
    int Tc = 1;
    for (int i = 0; i < 16; ++i) if (divs[i] <= tcmax) { Tc = divs[i]; break; }

    const int lds0 = (128 * XPAD + HID * HID) * (int)sizeof(float);
    const int lds1 = (HID * WPAD) * (int)sizeof(float);
    const int lds2 = (2 * HID * WPAD + HID * DOUT) * (int)sizeof(float);
    hipFuncSetAttribute((const void*)srnn_dense,
                        hipFuncAttributeMaxDynamicSharedMemorySize, lds0);
    hipFuncSetAttribute((const void*)srnn_layer1,
                        hipFuncAttributeMaxDynamicSharedMemorySize, lds1);
    hipFuncSetAttribute((const void*)srnn_layer2,
                        hipFuncAttributeMaxDynamicSharedMemorySize, lds2);

    for (int t0 = 0; t0 < T_STEPS; t0 += Tc) {
        srnn_dense<<<4 * Tc, 512, lds0, stream>>>(x, Wi1, D, t0, Tc);
        srnn_layer1<<<NS / 2, 128, lds1, stream>>>(D, Wh1, bi1, bh1, masks, state,
                                                   t0, Tc, t0 == 0 ? 1 : 0);
    }
    srnn_layer2<<<NS / 2, 128, lds2, stream>>>(masks, Wi2, bi2, Wh2, bh2, Wo, bo, out);
}